// Round 9
// baseline (237.692 us; speedup 1.0000x reference)
//
#include <hip/hip_runtime.h>
#include <stdint.h>

typedef unsigned short ushort_t;
typedef __attribute__((ext_vector_type(8))) short short8;
typedef __attribute__((ext_vector_type(4))) short short4v;
typedef __attribute__((ext_vector_type(4))) float f32x4;
typedef __attribute__((ext_vector_type(16))) float f32x16;

#define B_ 4
#define T_ 2048
#define H_ 16
#define DH_ 64
#define DIM_ 1024
#define NE_ 3072
#define LOG2E 1.4426950408889634f

__device__ __forceinline__ ushort_t f2bf(float f) {
  union { float f; uint32_t u; } v; v.f = f;
  uint32_t u = v.u;
  uint32_t r = (u + 0x7FFFu + ((u >> 16) & 1u)) >> 16;  // RNE
  return (ushort_t)r;
}
__device__ __forceinline__ void gload16(const void* g, void* l) {
  __builtin_amdgcn_global_load_lds(
      (__attribute__((address_space(1))) void*)g,
      (__attribute__((address_space(3))) void*)l, 16, 0, 0);
}
__device__ __forceinline__ uint32_t cvtpk(float a, float b) {
  uint32_t r;
  asm("v_cvt_pk_bf16_f32 %0, %1, %2" : "=v"(r) : "v"(a), "v"(b));
  return r;
}
__device__ __forceinline__ float exp2_asm(float x) {
  float r; asm("v_exp_f32 %0, %1" : "=v"(r) : "v"(x)); return r;
}

// fused 3-tensor f32 -> bf16 convert (one launch)
__global__ __launch_bounds__(256)
void cvt3(const float* __restrict__ a, ushort_t* __restrict__ oa, long nba,
          const float* __restrict__ b, ushort_t* __restrict__ ob, long nbb,
          const float* __restrict__ c, ushort_t* __restrict__ oc) {
  long i = ((long)blockIdx.x * 256 + threadIdx.x) * 4;
  const float* src; ushort_t* dst;
  if (i < nba)            { src = a; dst = oa; }
  else if (i < nba + nbb) { src = b; dst = ob; i -= nba; }
  else                    { src = c; dst = oc; i -= nba + nbb; }
  const float4 v = *(const float4*)(src + i);
  short4v o;
  o[0] = (short)f2bf(v.x); o[1] = (short)f2bf(v.y);
  o[2] = (short)f2bf(v.z); o[3] = (short)f2bf(v.w);
  *(short4v*)(dst + i) = o;
}

#define MFMA16(a, b, c) __builtin_amdgcn_mfma_f32_16x16x32_bf16(a, b, c, 0, 0, 0)
#define MFMA32(a, b, c) __builtin_amdgcn_mfma_f32_32x32x16_bf16(a, b, c, 0, 0, 0)

// 256x256-tile GEMM, BK=64, 8 waves (2Mx4N), 128KB LDS double-buffer,
// depth-1 prefetch + 4 quadrant-phases/K-tile (T2 swizzle + T3/T4 + T5).
// C[m][n] = sum_k A[m][k]*B[n][k], both row-major bf16 K-contiguous.
// MODE 0: bf16 out; cols with kk==0 scaled by LOG2E/32. MODE 1: f32 out + bias.
// LDS[r][slot s] = G[r][s ^ (r&7)] (16B slots), staged via pre-swizzled src.
template<int MODE>
__global__ __launch_bounds__(512, 2)
void gemm256(const ushort_t* __restrict__ A, const ushort_t* __restrict__ Bm,
             ushort_t* __restrict__ Cb, float* __restrict__ Cf,
             const float* __restrict__ bias, int M, int N, int K, int nb) {
  __shared__ __align__(16) ushort_t Al[2][256 * 64];
  __shared__ __align__(16) ushort_t Bl[2][256 * 64];
  const int tid = threadIdx.x;
  const int wave = tid >> 6, lane = tid & 63;
  const int cpx = gridDim.x >> 3;
  const int bid = (blockIdx.x & 7) * cpx + (blockIdx.x >> 3);  // T1 swizzle
  const int bm0 = (bid / nb) << 8, bn0 = (bid % nb) << 8;
  const int l4 = lane >> 4, l15 = lane & 15;
  const int l7 = lane & 7, l8 = lane >> 3;
  const int wm = wave >> 2, wn = wave & 3;       // 2 x 4 wave grid
  const int wrow0 = wm * 128, wcol0 = wn * 64;   // per-wave C: 128 x 64

  const int sl = (l7 ^ l8) * 8;   // pre-swizzled global slot (elements)
  const int r0a = wave * 32;      // rows this wave stages (32 of A, 32 of B)

#define GSTAGE(bufi, kk0)                                                          \
  do {                                                                             \
    _Pragma("unroll")                                                              \
    for (int c = 0; c < 4; ++c) {                                                  \
      const int rr = r0a + c * 8 + l8;                                             \
      gload16(A + (long)(bm0 + rr) * K + (kk0) + sl, &Al[bufi][(r0a + c * 8) * 64]); \
      gload16(Bm + (long)(bn0 + rr) * K + (kk0) + sl, &Bl[bufi][(r0a + c * 8) * 64]); \
    }                                                                              \
  } while (0)

  f32x4 acc[8][4];
#pragma unroll
  for (int i = 0; i < 8; ++i)
#pragma unroll
    for (int j = 0; j < 4; ++j) acc[i][j] = {0.f, 0.f, 0.f, 0.f};

  // prologue: stage tile 0 into buf 0
  GSTAGE(0, 0);
  asm volatile("s_waitcnt vmcnt(0)" ::: "memory");
  __builtin_amdgcn_sched_barrier(0);
  __builtin_amdgcn_s_barrier();
  __builtin_amdgcn_sched_barrier(0);

  const int NT = K >> 6;
  int buf = 0;
  for (int kt = 0; kt < NT; ++kt) {
    const int k0 = kt << 6;
    const ushort_t* Ab = &Al[buf][0];
    const ushort_t* Bb = &Bl[buf][0];
    short8 af[4][2];  // A-frags of current M-half, live across 2 phases
#pragma unroll
    for (int p = 0; p < 4; ++p) {
      const int mh = p >> 1, nh = p & 1;
      // ds-read fragments (swizzled): slot wanted g=4kk+l4, stored at g^(row&7)
      if (nh == 0) {
#pragma unroll
        for (int fi = 0; fi < 4; ++fi) {
          const int ar = wrow0 + mh * 64 + fi * 16 + l15;
#pragma unroll
          for (int kk = 0; kk < 2; ++kk)
            af[fi][kk] = *(const short8*)(Ab + ar * 64 + ((4 * kk + l4) ^ l7) * 8);
        }
      }
      short8 bf2[2][2];
#pragma unroll
      for (int fj = 0; fj < 2; ++fj) {
        const int br = wcol0 + nh * 32 + fj * 16 + l15;
#pragma unroll
        for (int kk = 0; kk < 2; ++kk)
          bf2[fj][kk] = *(const short8*)(Bb + br * 64 + ((4 * kk + l4) ^ l7) * 8);
      }
      if (p == 0 && kt < NT - 1) GSTAGE(buf ^ 1, k0 + 64);  // depth-1 prefetch

      __builtin_amdgcn_sched_barrier(0);
      __builtin_amdgcn_s_barrier();
      __builtin_amdgcn_sched_barrier(0);
      __builtin_amdgcn_s_setprio(1);
#pragma unroll
      for (int fi = 0; fi < 4; ++fi)
#pragma unroll
        for (int fj = 0; fj < 2; ++fj)
#pragma unroll
          for (int kk = 0; kk < 2; ++kk)
            acc[mh * 4 + fi][nh * 2 + fj] =
                MFMA16(af[fi][kk], bf2[fj][kk], acc[mh * 4 + fi][nh * 2 + fj]);
      __builtin_amdgcn_s_setprio(0);
      __builtin_amdgcn_sched_barrier(0);
      if (p == 3) {  // tile kt+1's 8 loads are the only outstanding: counted drain
        asm volatile("s_waitcnt vmcnt(0)" ::: "memory");
        __builtin_amdgcn_sched_barrier(0);
      }
      __builtin_amdgcn_s_barrier();
      __builtin_amdgcn_sched_barrier(0);
    }
    buf ^= 1;
  }

  // epilogue
#pragma unroll
  for (int fi = 0; fi < 8; ++fi) {
    const int row = bm0 + wrow0 + fi * 16 + l4 * 4;
#pragma unroll
    for (int fj = 0; fj < 4; ++fj) {
      const int col = bn0 + wcol0 + fj * 16 + l15;
      if (MODE == 0) {
        const float mult = (((col >> 4) % 3) == 0) ? 0.04508422f : 1.f;
#pragma unroll
        for (int r = 0; r < 4; ++r)
          Cb[(long)(row + r) * N + col] = f2bf(acc[fi][fj][r] * mult);
      } else {
        const float add = bias[col];
#pragma unroll
        for (int r = 0; r < 4; ++r)
          Cf[(long)(row + r) * N + col] = acc[fi][fj][r] + add;
      }
    }
  }
#undef GSTAGE
}

// qkv[b,t,e] (e = 48d+16kk+h) -> Q[b,h,t,d], K[b,h,t,d], Vt[b,h,d,t]
__global__ __launch_bounds__(256)
void reorg(const ushort_t* __restrict__ qkv, ushort_t* __restrict__ Qh,
           ushort_t* __restrict__ Kh, ushort_t* __restrict__ Vth) {
  __shared__ __align__(16) ushort_t lds[8 * 3080];
  const int bid = blockIdx.x;
  const int tt = bid & 255, b = bid >> 8;
  const int t0 = tt * 8;
  const int tid = threadIdx.x;
  const short8* src = (const short8*)(qkv + ((long)(b * T_ + t0)) * NE_);
  short8* dst = (short8*)lds;
  for (int i = tid; i < 8 * 384; i += 256) {
    const int r = i / 384, c = i - r * 384;
    dst[r * 385 + c] = src[i];
  }
  __syncthreads();
  for (int i = tid; i < 16 * 8 * 8; i += 256) {
    const int dblk = i & 7, t = (i >> 3) & 7, h = i >> 6;
    short8 vq, vk;
#pragma unroll
    for (int e = 0; e < 8; ++e) {
      const int d = dblk * 8 + e;
      vq[e] = (short)lds[t * 3080 + d * 48 + h];
      vk[e] = (short)lds[t * 3080 + d * 48 + 16 + h];
    }
    const long o = ((long)((b * H_ + h) * T_) + t0 + t) * DH_ + dblk * 8;
    *(short8*)(Qh + o) = vq;
    *(short8*)(Kh + o) = vk;
  }
  for (int i = tid; i < 16 * 64; i += 256) {
    const int d = i & 63, h = i >> 6;
    short8 v0;
#pragma unroll
    for (int t = 0; t < 8; ++t) v0[t] = (short)lds[t * 3080 + d * 48 + 32 + h];
    const long o = ((long)((b * H_ + h) * DH_) + d) * T_ + t0;
    *(short8*)(Vth + o) = v0;
  }
}

// flash attention v6 (round-7 verified): 4 waves x 32 q, KV tile 64, dbuf,
// 1 barrier/iter, diet softmax (log2-domain, no max tracking).
__global__ __launch_bounds__(256, 4)
void attn_fwd6(const ushort_t* __restrict__ Qh, const ushort_t* __restrict__ Kh,
               const ushort_t* __restrict__ Vth, ushort_t* __restrict__ aout) {
  __shared__ __align__(16) ushort_t Kt[2][64 * 64];
  __shared__ __align__(16) ushort_t Vts[2][64 * 64];
  const int bid = blockIdx.x;
  const int xcd = bid & 7, idx = bid >> 3;
  const int bh = xcd + ((idx & 7) << 3);
  const int qb = idx >> 3;
  const int tid = threadIdx.x, wv = tid >> 6, lane = tid & 63;
  const int l31 = lane & 31, hi = lane >> 5, l7 = lane & 7, l8 = lane >> 3;
  const ushort_t* Qb = Qh + (long)bh * T_ * DH_;
  const ushort_t* Kb = Kh + (long)bh * T_ * DH_;
  const ushort_t* Vb = Vth + (long)bh * DH_ * T_;
  const int q = qb * 128 + wv * 32 + l31;

  short8 qf[4];
#pragma unroll
  for (int s = 0; s < 4; ++s)
    qf[s] = *(const short8*)(Qb + (long)q * DH_ + s * 16 + hi * 8);

  f32x16 acc0, acc1, z16;
#pragma unroll
  for (int i = 0; i < 16; ++i) { acc0[i] = 0.f; acc1[i] = 0.f; z16[i] = 0.f; }
  float lsum_part = 0.f;

  const int r0a = wv * 16;
  const int sl = ((l7 ^ l8) * 8);

#define STAGE(bufi, jj)                                                          \
  do {                                                                           \
    _Pragma("unroll")                                                            \
    for (int c = 0; c < 2; ++c) {                                                \
      const int rr = r0a + c * 8 + l8;                                           \
      gload16(Kb + (long)((jj) + rr) * DH_ + sl, &Kt[bufi][(r0a + c * 8) * 64]); \
      gload16(Vb + (long)rr * T_ + (jj) + sl, &Vts[bufi][(r0a + c * 8) * 64]);   \
    }                                                                            \
  } while (0)

  STAGE(0, 0);
  asm volatile("s_waitcnt vmcnt(0)" ::: "memory");
  __builtin_amdgcn_sched_barrier(0);
  __builtin_amdgcn_s_barrier();
  __builtin_amdgcn_sched_barrier(0);

  int buf = 0;
  for (int j0 = 0; j0 < T_; j0 += 64) {
    STAGE(buf ^ 1, (j0 + 64) & (T_ - 1));

    const ushort_t* Ktb = &Kt[buf][0];
    const ushort_t* Vtb = &Vts[buf][0];

    f32x16 sb0, sb1;
    __builtin_amdgcn_s_setprio(1);
#pragma unroll
    for (int s = 0; s < 4; ++s) {
      const int so = ((2 * s + hi) ^ l7) * 8;
      const short8 k0 = *(const short8*)(Ktb + (l31) * 64 + so);
      const short8 k1 = *(const short8*)(Ktb + (32 + l31) * 64 + so);
      sb0 = MFMA32(k0, qf[s], (s == 0) ? z16 : sb0);
      sb1 = MFMA32(k1, qf[s], (s == 0) ? z16 : sb1);
    }
    __builtin_amdgcn_s_setprio(0);

    float r0 = 0.f, r1 = 0.f, r2 = 0.f, r3 = 0.f;
#pragma unroll
    for (int i = 0; i < 16; i += 4) {
      sb0[i]     = exp2_asm(sb0[i]);     r0 += sb0[i];
      sb0[i + 1] = exp2_asm(sb0[i + 1]); r1 += sb0[i + 1];
      sb0[i + 2] = exp2_asm(sb0[i + 2]); r2 += sb0[i + 2];
      sb0[i + 3] = exp2_asm(sb0[i + 3]); r3 += sb0[i + 3];
    }
#pragma unroll
    for (int i = 0; i < 16; i += 4) {
      sb1[i]     = exp2_asm(sb1[i]);     r0 += sb1[i];
      sb1[i + 1] = exp2_asm(sb1[i + 1]); r1 += sb1[i + 1];
      sb1[i + 2] = exp2_asm(sb1[i + 2]); r2 += sb1[i + 2];
      sb1[i + 3] = exp2_asm(sb1[i + 3]); r3 += sb1[i + 3];
    }
    lsum_part += (r0 + r1) + (r2 + r3);

    short8 pf[4];
#pragma unroll
    for (int ks = 0; ks < 4; ++ks) {
      const f32x16& S = (ks < 2) ? sb0 : sb1;
      const int rb = (ks & 1) * 8;
      uint32_t wE0 = cvtpk(S[rb + 0], S[rb + 1]);
      uint32_t wE1 = cvtpk(S[rb + 2], S[rb + 3]);
      uint32_t wO0 = cvtpk(S[rb + 4], S[rb + 5]);
      uint32_t wO1 = cvtpk(S[rb + 6], S[rb + 7]);
      asm("v_permlane32_swap_b32 %0, %1" : "+v"(wE0), "+v"(wO0));
      asm("v_permlane32_swap_b32 %0, %1" : "+v"(wE1), "+v"(wO1));
      union { uint32_t u[4]; short8 v; } pk;
      pk.u[0] = wE0; pk.u[1] = wE1; pk.u[2] = wO0; pk.u[3] = wO1;
      pf[ks] = pk.v;
    }

    __builtin_amdgcn_s_setprio(1);
#pragma unroll
    for (int ks = 0; ks < 4; ++ks) {
      const int so = ((2 * ks + hi) ^ l7) * 8;
      const short8 v0 = *(const short8*)(Vtb + (l31) * 64 + so);
      const short8 v1 = *(const short8*)(Vtb + (32 + l31) * 64 + so);
      acc0 = MFMA32(v0, pf[ks], acc0);
      acc1 = MFMA32(v1, pf[ks], acc1);
    }
    __builtin_amdgcn_s_setprio(0);

    asm volatile("s_waitcnt vmcnt(0)" ::: "memory");
    __builtin_amdgcn_sched_barrier(0);
    __builtin_amdgcn_s_barrier();
    __builtin_amdgcn_sched_barrier(0);
    buf ^= 1;
  }

  const float lsum = lsum_part + __shfl_xor(lsum_part, 32);
  const float inv = 1.f / lsum;
  const int b = bh >> 4, h = bh & 15;
  ushort_t* orow = aout + ((long)(b * T_ + q)) * DIM_ + h * DH_;
#pragma unroll
  for (int vb = 0; vb < 2; ++vb)
#pragma unroll
    for (int rg = 0; rg < 4; ++rg) {
      short4v o4;
#pragma unroll
      for (int e = 0; e < 4; ++e) {
        const float val = ((vb == 0) ? acc0[rg * 4 + e] : acc1[rg * 4 + e]) * inv;
        o4[e] = (short)f2bf(val);
      }
      *(short4v*)(orow + vb * 32 + rg * 8 + hi * 4) = o4;
    }
#undef STAGE
}

extern "C" void kernel_launch(void* const* d_in, const int* in_sizes, int n_in,
                              void* d_out, int out_size, void* d_ws, size_t ws_size,
                              hipStream_t stream) {
  const float* x_f    = (const float*)d_in[0];
  const float* wqkv_f = (const float*)d_in[1];
  const float* wout_f = (const float*)d_in[2];
  const float* bout_f = (const float*)d_in[3];
  float* out = (float*)d_out;

  ushort_t* wqkv_bf = (ushort_t*)d_ws;
  ushort_t* wout_bf = wqkv_bf + (long)NE_ * DIM_;
  ushort_t* qkv     = wout_bf + (long)DIM_ * DIM_;
  ushort_t* R       = qkv + (long)B_ * T_ * NE_;
  ushort_t* x_bf = R;
  ushort_t* Qh   = R;
  ushort_t* Kh   = R + (long)B_ * H_ * T_ * DH_;
  ushort_t* Vth  = Kh + (long)B_ * H_ * T_ * DH_;
  ushort_t* aout = qkv;

  const long n_x = (long)B_ * T_ * DIM_;       // 8,388,608
  const long n_wq = (long)NE_ * DIM_;          // 3,145,728
  cvt3<<<dim3((int)((n_x + n_wq + (long)DIM_ * DIM_) / 1024)), dim3(256), 0, stream>>>(
      x_f, x_bf, n_x, wqkv_f, wqkv_bf, n_wq, wout_f, wout_bf);

  gemm256<0><<<dim3((8192 / 256) * (3072 / 256)), dim3(512), 0, stream>>>(
      x_bf, wqkv_bf, qkv, nullptr, nullptr, 8192, 3072, 1024, 3072 / 256);
  reorg<<<dim3(1024), dim3(256), 0, stream>>>(qkv, Qh, Kh, Vth);
  attn_fwd6<<<dim3(1024), dim3(256), 0, stream>>>(Qh, Kh, Vth, aout);
  gemm256<1><<<dim3((8192 / 256) * (1024 / 256)), dim3(512), 0, stream>>>(
      aout, wout_bf, nullptr, out, bout_f, 8192, 1024, 1024, 1024 / 256);
}

// Round 11
// 210.416 us; speedup vs baseline: 1.1296x; 1.1296x over previous
//
#include <hip/hip_runtime.h>
#include <stdint.h>

typedef unsigned short ushort_t;
typedef __attribute__((ext_vector_type(8))) short short8;
typedef __attribute__((ext_vector_type(4))) short short4v;
typedef __attribute__((ext_vector_type(4))) float f32x4;
typedef __attribute__((ext_vector_type(16))) float f32x16;

#define B_ 4
#define T_ 2048
#define H_ 16
#define DH_ 64
#define DIM_ 1024
#define NE_ 3072
#define LOG2E 1.4426950408889634f

__device__ __forceinline__ ushort_t f2bf(float f) {
  union { float f; uint32_t u; } v; v.f = f;
  uint32_t u = v.u;
  uint32_t r = (u + 0x7FFFu + ((u >> 16) & 1u)) >> 16;  // RNE
  return (ushort_t)r;
}
__device__ __forceinline__ void gload16(const void* g, void* l) {
  __builtin_amdgcn_global_load_lds(
      (__attribute__((address_space(1))) void*)g,
      (__attribute__((address_space(3))) void*)l, 16, 0, 0);
}
__device__ __forceinline__ uint32_t cvtpk(float a, float b) {
  uint32_t r;
  asm("v_cvt_pk_bf16_f32 %0, %1, %2" : "=v"(r) : "v"(a), "v"(b));
  return r;
}
__device__ __forceinline__ float exp2_asm(float x) {
  float r; asm("v_exp_f32 %0, %1" : "=v"(r) : "v"(x)); return r;
}

// fused 3-tensor f32 -> bf16 convert (one launch)
__global__ __launch_bounds__(256)
void cvt3(const float* __restrict__ a, ushort_t* __restrict__ oa, long nba,
          const float* __restrict__ b, ushort_t* __restrict__ ob, long nbb,
          const float* __restrict__ c, ushort_t* __restrict__ oc) {
  long i = ((long)blockIdx.x * 256 + threadIdx.x) * 4;
  const float* src; ushort_t* dst;
  if (i < nba)            { src = a; dst = oa; }
  else if (i < nba + nbb) { src = b; dst = ob; i -= nba; }
  else                    { src = c; dst = oc; i -= nba + nbb; }
  const float4 v = *(const float4*)(src + i);
  short4v o;
  o[0] = (short)f2bf(v.x); o[1] = (short)f2bf(v.y);
  o[2] = (short)f2bf(v.z); o[3] = (short)f2bf(v.w);
  *(short4v*)(dst + i) = o;
}

#define MFMA16(a, b, c) __builtin_amdgcn_mfma_f32_16x16x32_bf16(a, b, c, 0, 0, 0)
#define MFMA32(a, b, c) __builtin_amdgcn_mfma_f32_32x32x16_bf16(a, b, c, 0, 0, 0)

// 128^2-tile GEMM, BK=64 (2 barriers per 64-K, halved vs BK=32), with the
// T2 both-sides XOR swizzle: LDS[r][slot s] = G[r][s ^ (r&7)] (16B slots),
// staged via pre-swizzled global source; reads at slot (kk*4+l4)^(r&7).
// Residual 2-way conflict (row vs row+8) is free (m136).
// C[m][n] = sum_k A[m][k]*B[n][k], row-major bf16, K contiguous.
// MODE 0: bf16 out; q-cols (kk==0) scaled by LOG2E/32. MODE 1: f32 out + bias.
template<int MODE>
__global__ __launch_bounds__(256)
void gemm_bt(const ushort_t* __restrict__ A, const ushort_t* __restrict__ Bm,
             ushort_t* __restrict__ Cb, float* __restrict__ Cf,
             const float* __restrict__ bias, int M, int N, int K, int nb) {
  __shared__ __align__(16) ushort_t Alds[128 * 64];
  __shared__ __align__(16) ushort_t Blds[128 * 64];
  const int tid = threadIdx.x;
  const int wave = tid >> 6, lane = tid & 63;
  const int cpx = gridDim.x >> 3;
  const int bid = (blockIdx.x & 7) * cpx + (blockIdx.x >> 3);  // T1 swizzle
  const int bm0 = (bid / nb) << 7, bn0 = (bid % nb) << 7;
  const int l4 = lane >> 4, l15 = lane & 15;
  const int l7 = lane & 7, l8 = lane >> 3;
  const int sl = (l7 ^ l8) * 8;        // pre-swizzled global slot (elements)
  const int wr = (wave >> 1) * 64, wc = (wave & 1) * 64;

  f32x4 acc[4][4];
#pragma unroll
  for (int i = 0; i < 4; ++i)
#pragma unroll
    for (int j = 0; j < 4; ++j) acc[i][j] = {0.f, 0.f, 0.f, 0.f};

  for (int k0 = 0; k0 < K; k0 += 64) {
    __syncthreads();
    // stage 128x64 of A and B: per wave 4 gloads each (8 rows per gload)
#pragma unroll
    for (int c = 0; c < 4; ++c) {
      const int r0 = wave * 32 + c * 8;
      gload16(A + (long)(bm0 + r0 + l8) * K + k0 + sl, Alds + r0 * 64);
      gload16(Bm + (long)(bn0 + r0 + l8) * K + k0 + sl, Blds + r0 * 64);
    }
    __syncthreads();
#pragma unroll
    for (int kk = 0; kk < 2; ++kk) {
      short8 af[4], bfr[4];
#pragma unroll
      for (int i = 0; i < 4; ++i) {
        const int ar = wr + i * 16 + l15;
        af[i] = *(const short8*)(Alds + ar * 64 + ((kk * 4 + l4) ^ (ar & 7)) * 8);
      }
#pragma unroll
      for (int j = 0; j < 4; ++j) {
        const int br = wc + j * 16 + l15;
        bfr[j] = *(const short8*)(Blds + br * 64 + ((kk * 4 + l4) ^ (br & 7)) * 8);
      }
#pragma unroll
      for (int i = 0; i < 4; ++i)
#pragma unroll
        for (int j = 0; j < 4; ++j)
          acc[i][j] = MFMA16(af[i], bfr[j], acc[i][j]);
    }
  }

#pragma unroll
  for (int i = 0; i < 4; ++i) {
    const int row = bm0 + wr + i * 16 + l4 * 4;
#pragma unroll
    for (int j = 0; j < 4; ++j) {
      const int col = bn0 + wc + j * 16 + l15;
      if (MODE == 0) {
        const float mult = (((col >> 4) % 3) == 0) ? 0.04508422f : 1.f;
#pragma unroll
        for (int r = 0; r < 4; ++r)
          Cb[(long)(row + r) * N + col] = f2bf(acc[i][j][r] * mult);
      } else {
        const float add = bias[col];
#pragma unroll
        for (int r = 0; r < 4; ++r)
          Cf[(long)(row + r) * N + col] = acc[i][j][r] + add;
      }
    }
  }
}

// qkv[b,t,e] (e = 48d+16kk+h) -> Q[b,h,t,d], K[b,h,t,d], Vt[b,h,d,t]
__global__ __launch_bounds__(256)
void reorg(const ushort_t* __restrict__ qkv, ushort_t* __restrict__ Qh,
           ushort_t* __restrict__ Kh, ushort_t* __restrict__ Vth) {
  __shared__ __align__(16) ushort_t lds[8 * 3080];
  const int bid = blockIdx.x;
  const int tt = bid & 255, b = bid >> 8;
  const int t0 = tt * 8;
  const int tid = threadIdx.x;
  const short8* src = (const short8*)(qkv + ((long)(b * T_ + t0)) * NE_);
  short8* dst = (short8*)lds;
  for (int i = tid; i < 8 * 384; i += 256) {
    const int r = i / 384, c = i - r * 384;
    dst[r * 385 + c] = src[i];
  }
  __syncthreads();
  for (int i = tid; i < 16 * 8 * 8; i += 256) {
    const int dblk = i & 7, t = (i >> 3) & 7, h = i >> 6;
    short8 vq, vk;
#pragma unroll
    for (int e = 0; e < 8; ++e) {
      const int d = dblk * 8 + e;
      vq[e] = (short)lds[t * 3080 + d * 48 + h];
      vk[e] = (short)lds[t * 3080 + d * 48 + 16 + h];
    }
    const long o = ((long)((b * H_ + h) * T_) + t0 + t) * DH_ + dblk * 8;
    *(short8*)(Qh + o) = vq;
    *(short8*)(Kh + o) = vk;
  }
  for (int i = tid; i < 16 * 64; i += 256) {
    const int d = i & 63, h = i >> 6;
    short8 v0;
#pragma unroll
    for (int t = 0; t < 8; ++t) v0[t] = (short)lds[t * 3080 + d * 48 + 32 + h];
    const long o = ((long)((b * H_ + h) * DH_) + d) * T_ + t0;
    *(short8*)(Vth + o) = v0;
  }
}

// flash attention v6 (verified, 84us): 4 waves x 32 q, KV tile 64, dbuf,
// 1 barrier/iter, diet softmax (log2-domain, no max tracking).
__global__ __launch_bounds__(256, 4)
void attn_fwd6(const ushort_t* __restrict__ Qh, const ushort_t* __restrict__ Kh,
               const ushort_t* __restrict__ Vth, ushort_t* __restrict__ aout) {
  __shared__ __align__(16) ushort_t Kt[2][64 * 64];
  __shared__ __align__(16) ushort_t Vts[2][64 * 64];
  const int bid = blockIdx.x;
  const int xcd = bid & 7, idx = bid >> 3;
  const int bh = xcd + ((idx & 7) << 3);
  const int qb = idx >> 3;
  const int tid = threadIdx.x, wv = tid >> 6, lane = tid & 63;
  const int l31 = lane & 31, hi = lane >> 5, l7 = lane & 7, l8 = lane >> 3;
  const ushort_t* Qb = Qh + (long)bh * T_ * DH_;
  const ushort_t* Kb = Kh + (long)bh * T_ * DH_;
  const ushort_t* Vb = Vth + (long)bh * DH_ * T_;
  const int q = qb * 128 + wv * 32 + l31;

  short8 qf[4];
#pragma unroll
  for (int s = 0; s < 4; ++s)
    qf[s] = *(const short8*)(Qb + (long)q * DH_ + s * 16 + hi * 8);

  f32x16 acc0, acc1, z16;
#pragma unroll
  for (int i = 0; i < 16; ++i) { acc0[i] = 0.f; acc1[i] = 0.f; z16[i] = 0.f; }
  float lsum_part = 0.f;

  const int r0a = wv * 16;
  const int sl = ((l7 ^ l8) * 8);

#define STAGE(bufi, jj)                                                          \
  do {                                                                           \
    _Pragma("unroll")                                                            \
    for (int c = 0; c < 2; ++c) {                                                \
      const int rr = r0a + c * 8 + l8;                                           \
      gload16(Kb + (long)((jj) + rr) * DH_ + sl, &Kt[bufi][(r0a + c * 8) * 64]); \
      gload16(Vb + (long)rr * T_ + (jj) + sl, &Vts[bufi][(r0a + c * 8) * 64]);   \
    }                                                                            \
  } while (0)

  STAGE(0, 0);
  asm volatile("s_waitcnt vmcnt(0)" ::: "memory");
  __builtin_amdgcn_sched_barrier(0);
  __builtin_amdgcn_s_barrier();
  __builtin_amdgcn_sched_barrier(0);

  int buf = 0;
  for (int j0 = 0; j0 < T_; j0 += 64) {
    STAGE(buf ^ 1, (j0 + 64) & (T_ - 1));

    const ushort_t* Ktb = &Kt[buf][0];
    const ushort_t* Vtb = &Vts[buf][0];

    f32x16 sb0, sb1;
    __builtin_amdgcn_s_setprio(1);
#pragma unroll
    for (int s = 0; s < 4; ++s) {
      const int so = ((2 * s + hi) ^ l7) * 8;
      const short8 k0 = *(const short8*)(Ktb + (l31) * 64 + so);
      const short8 k1 = *(const short8*)(Ktb + (32 + l31) * 64 + so);
      sb0 = MFMA32(k0, qf[s], (s == 0) ? z16 : sb0);
      sb1 = MFMA32(k1, qf[s], (s == 0) ? z16 : sb1);
    }
    __builtin_amdgcn_s_setprio(0);

    float r0 = 0.f, r1 = 0.f, r2 = 0.f, r3 = 0.f;
#pragma unroll
    for (int i = 0; i < 16; i += 4) {
      sb0[i]     = exp2_asm(sb0[i]);     r0 += sb0[i];
      sb0[i + 1] = exp2_asm(sb0[i + 1]); r1 += sb0[i + 1];
      sb0[i + 2] = exp2_asm(sb0[i + 2]); r2 += sb0[i + 2];
      sb0[i + 3] = exp2_asm(sb0[i + 3]); r3 += sb0[i + 3];
    }
#pragma unroll
    for (int i = 0; i < 16; i += 4) {
      sb1[i]     = exp2_asm(sb1[i]);     r0 += sb1[i];
      sb1[i + 1] = exp2_asm(sb1[i + 1]); r1 += sb1[i + 1];
      sb1[i + 2] = exp2_asm(sb1[i + 2]); r2 += sb1[i + 2];
      sb1[i + 3] = exp2_asm(sb1[i + 3]); r3 += sb1[i + 3];
    }
    lsum_part += (r0 + r1) + (r2 + r3);

    short8 pf[4];
#pragma unroll
    for (int ks = 0; ks < 4; ++ks) {
      const f32x16& S = (ks < 2) ? sb0 : sb1;
      const int rb = (ks & 1) * 8;
      uint32_t wE0 = cvtpk(S[rb + 0], S[rb + 1]);
      uint32_t wE1 = cvtpk(S[rb + 2], S[rb + 3]);
      uint32_t wO0 = cvtpk(S[rb + 4], S[rb + 5]);
      uint32_t wO1 = cvtpk(S[rb + 6], S[rb + 7]);
      asm("v_permlane32_swap_b32 %0, %1" : "+v"(wE0), "+v"(wO0));
      asm("v_permlane32_swap_b32 %0, %1" : "+v"(wE1), "+v"(wO1));
      union { uint32_t u[4]; short8 v; } pk;
      pk.u[0] = wE0; pk.u[1] = wE1; pk.u[2] = wO0; pk.u[3] = wO1;
      pf[ks] = pk.v;
    }

    __builtin_amdgcn_s_setprio(1);
#pragma unroll
    for (int ks = 0; ks < 4; ++ks) {
      const int so = ((2 * ks + hi) ^ l7) * 8;
      const short8 v0 = *(const short8*)(Vtb + (l31) * 64 + so);
      const short8 v1 = *(const short8*)(Vtb + (32 + l31) * 64 + so);
      acc0 = MFMA32(v0, pf[ks], acc0);
      acc1 = MFMA32(v1, pf[ks], acc1);
    }
    __builtin_amdgcn_s_setprio(0);

    asm volatile("s_waitcnt vmcnt(0)" ::: "memory");
    __builtin_amdgcn_sched_barrier(0);
    __builtin_amdgcn_s_barrier();
    __builtin_amdgcn_sched_barrier(0);
    buf ^= 1;
  }

  const float lsum = lsum_part + __shfl_xor(lsum_part, 32);
  const float inv = 1.f / lsum;
  const int b = bh >> 4, h = bh & 15;
  ushort_t* orow = aout + ((long)(b * T_ + q)) * DIM_ + h * DH_;
#pragma unroll
  for (int vb = 0; vb < 2; ++vb)
#pragma unroll
    for (int rg = 0; rg < 4; ++rg) {
      short4v o4;
#pragma unroll
      for (int e = 0; e < 4; ++e) {
        const float val = ((vb == 0) ? acc0[rg * 4 + e] : acc1[rg * 4 + e]) * inv;
        o4[e] = (short)f2bf(val);
      }
      *(short4v*)(orow + vb * 32 + rg * 8 + hi * 4) = o4;
    }
#undef STAGE
}

extern "C" void kernel_launch(void* const* d_in, const int* in_sizes, int n_in,
                              void* d_out, int out_size, void* d_ws, size_t ws_size,
                              hipStream_t stream) {
  const float* x_f    = (const float*)d_in[0];
  const float* wqkv_f = (const float*)d_in[1];
  const float* wout_f = (const float*)d_in[2];
  const float* bout_f = (const float*)d_in[3];
  float* out = (float*)d_out;

  ushort_t* wqkv_bf = (ushort_t*)d_ws;
  ushort_t* wout_bf = wqkv_bf + (long)NE_ * DIM_;
  ushort_t* qkv     = wout_bf + (long)DIM_ * DIM_;
  ushort_t* R       = qkv + (long)B_ * T_ * NE_;
  ushort_t* x_bf = R;
  ushort_t* Qh   = R;
  ushort_t* Kh   = R + (long)B_ * H_ * T_ * DH_;
  ushort_t* Vth  = Kh + (long)B_ * H_ * T_ * DH_;
  ushort_t* aout = qkv;

  const long n_x = (long)B_ * T_ * DIM_;       // 8,388,608
  const long n_wq = (long)NE_ * DIM_;          // 3,145,728
  cvt3<<<dim3((int)((n_x + n_wq + (long)DIM_ * DIM_) / 1024)), dim3(256), 0, stream>>>(
      x_f, x_bf, n_x, wqkv_f, wqkv_bf, n_wq, wout_f, wout_bf);

  gemm_bt<0><<<dim3((8192 / 128) * (3072 / 128)), dim3(256), 0, stream>>>(
      x_bf, wqkv_bf, qkv, nullptr, nullptr, 8192, 3072, 1024, 3072 / 128);
  reorg<<<dim3(1024), dim3(256), 0, stream>>>(qkv, Qh, Kh, Vth);
  attn_fwd6<<<dim3(1024), dim3(256), 0, stream>>>(Qh, Kh, Vth, aout);
  gemm_bt<1><<<dim3((8192 / 128) * (1024 / 128)), dim3(256), 0, stream>>>(
      aout, wout_bf, nullptr, out, bout_f, 8192, 1024, 1024, 1024 / 128);
}